// Round 1
// 715.283 us; speedup vs baseline: 1.0970x; 1.0970x over previous
//
#include <hip/hip_runtime.h>
#include <hip/hip_bf16.h>

// ---------------------------------------------------------------------------
// Hie_Couple live subgraph (xs_/A_s/C_M_S/bias_S/Vf dead in reference).
// All GEMMs on bf16 MFMA. entmax-1.5 via register-resident Newton.
// This round: 256^2 8-phase GEMM (T2+T3+T4+T5) for the two big GEMMs
// (scores, BT with split-K x2), vectorized S_s transpose stores, split-K
// reduce folded into entmax bias read.
// ---------------------------------------------------------------------------

typedef __attribute__((ext_vector_type(8))) short short8;
typedef __attribute__((ext_vector_type(4))) float floatx4;

#define GLOBAL_AS __attribute__((address_space(1)))
#define LDS_AS    __attribute__((address_space(3)))

struct alignas(4) bf2 { __hip_bfloat16 x, y; };
struct alignas(8) bf4 { __hip_bfloat16 v[4]; };

// ============================ bf16 MFMA GEMM ===============================
// (legacy 128x128 kernel, kept for the small linears / C_M / T1 / out1)
// C[M,N] = scale * A[M,K] @ Bt[N,K]^T (+ bias[col]); strides per blockIdx.z.
// Optional CT: bf16, per-RB-row-group transposed.
#define MT 128
#define NT 128
#define KT 64

template <typename OutT>
__global__ __launch_bounds__(256) void mfma_gemm(
    const __hip_bfloat16* __restrict__ A, const __hip_bfloat16* __restrict__ Bt,
    const float* __restrict__ bias, OutT* __restrict__ C,
    __hip_bfloat16* __restrict__ CT,
    int M, int N, int K,
    long sA, long sB, long sC, long sCT, int RB, float scale)
{
    __shared__ __hip_bfloat16 Asm[MT * KT];  // 16 KB
    __shared__ __hip_bfloat16 Bsm[NT * KT];  // 16 KB

    const int bz = blockIdx.z;
    const short* Ag = (const short*)(A + (long)bz * sA);
    const short* Bg = (const short*)(Bt + (long)bz * sB);

    const int m0 = blockIdx.x * MT;
    const int n0 = blockIdx.y * NT;

    const int tid  = threadIdx.x;
    const int lane = tid & 63;
    const int wm   = (tid >> 6 & 1) * 64;   // wave m-offset
    const int wn   = (tid >> 7) * 64;       // wave n-offset
    const int lm   = lane & 15;
    const int quad = lane >> 4;

    floatx4 acc[4][4] = {};

    for (int k0 = 0; k0 < K; k0 += KT) {
#pragma unroll
        for (int p = 0; p < 4; ++p) {
            const int idx = p * 256 + tid;
            const int row = idx >> 3;
            const int c8  = idx & 7;
            const int wbase = (p * 256 + (tid & 192)) * 16;  // wave-uniform base
            __builtin_amdgcn_global_load_lds(
                (const GLOBAL_AS void*)(Ag + (long)(m0 + row) * K + k0 + c8 * 8),
                (LDS_AS void*)((char*)Asm + wbase), 16, 0, 0);
            __builtin_amdgcn_global_load_lds(
                (const GLOBAL_AS void*)(Bg + (long)(n0 + row) * K + k0 + c8 * 8),
                (LDS_AS void*)((char*)Bsm + wbase), 16, 0, 0);
        }
        __syncthreads();

#pragma unroll
        for (int ks = 0; ks < KT / 32; ++ks) {
            short8 af[4], bf[4];
#pragma unroll
            for (int i = 0; i < 4; ++i) {
                af[i] = *(const short8*)((const short*)Asm + (wm + i * 16 + lm) * KT + ks * 32 + quad * 8);
                bf[i] = *(const short8*)((const short*)Bsm + (wn + i * 16 + lm) * KT + ks * 32 + quad * 8);
            }
#pragma unroll
            for (int i = 0; i < 4; ++i)
#pragma unroll
                for (int j = 0; j < 4; ++j)
                    acc[i][j] = __builtin_amdgcn_mfma_f32_16x16x32_bf16(af[i], bf[j], acc[i][j], 0, 0, 0);
        }
        __syncthreads();
    }

    float bb[4] = {0.f, 0.f, 0.f, 0.f};
    if (bias) {
#pragma unroll
        for (int j = 0; j < 4; ++j) bb[j] = bias[n0 + wn + lm + j * 16];
    }
    OutT* Cg = C ? C + (long)bz * sC : nullptr;
    __hip_bfloat16* CTg = CT ? CT + (long)bz * sCT : nullptr;

#pragma unroll
    for (int i = 0; i < 4; ++i) {
        const int row0 = m0 + wm + i * 16 + quad * 4;
#pragma unroll
        for (int j = 0; j < 4; ++j) {
            const int col = n0 + wn + lm + j * 16;
            float v[4];
#pragma unroll
            for (int r = 0; r < 4; ++r) v[r] = acc[i][j][r] * scale + bb[j];
            if (Cg) {
#pragma unroll
                for (int r = 0; r < 4; ++r)
                    Cg[(long)(row0 + r) * N + col] = (OutT)v[r];
            }
            if (CTg) {
                bf4 pk;
#pragma unroll
                for (int r = 0; r < 4; ++r) pk.v[r] = (__hip_bfloat16)v[r];
                const long b_i = row0 / RB, r_i = row0 % RB;
                *(bf4*)(CTg + b_i * (long)N * RB + (long)col * RB + r_i) = pk;
            }
        }
    }
}

// ======================= 256x256 8-phase MFMA GEMM =========================
// C[M,N] = scale * A[M,K']@Bt[N,K']^T, per-batch strides, optional split-K:
// blockIdx.z = batch*(1<<ksh) + kh; each block does K/(1<<ksh) of the K dim,
// writing its partial to C + batch*sC + kh*sCsplit.
// 512 threads = 8 waves (2M x 4N), per-wave 128x64 output (acc[2][2][4][2]).
// BK=64; LDS 128 KB (A,B x 2 buffers); 4 phases/K-tile x 16 MFMA.
// T2: slot ^= (row&7) swizzle (inverse-swizzled global src, swizzled ds_read).
// T3/T4: one half-tile staged per phase, counted vmcnt (never 0 mid-loop).
// T5: setprio around each MFMA cluster.  T1: XCD-bijective block swizzle.
//
// Stage schedule (tile t computed from buf b=t&1, nb=b^1):
//   ph1 reads A0,B0(t) | stages B1(t+1)->nb | vmcnt(4) guarantees A1(t)
//   ph2 reads A1(t)    | stages A0(t+1)->nb
//   ph3 reads B1(t)    | stages A1(t+1)->nb
//   ph4 re-reads A0(t) | stages B0(t+2)->b  | vmcnt(4) guarantees B0,B1,A0(t+1)
// Every staged region's last reader finished >=1 barrier before the issue.

#define G8_LDSA(B_, QR_) do { \
  _Pragma("unroll") for (int i_ = 0; i_ < 4; ++i_) { \
  _Pragma("unroll") for (int ks_ = 0; ks_ < 2; ++ks_) { \
    const int row_ = wm + (QR_) * 64 + i_ * 16 + lm; \
    af[i_][ks_] = *(const short8*)(lds_c + (B_) * 32768 + row_ * 128 + ((((ks_ << 2) | qd) ^ sw) << 4)); } } } while (0)

#define G8_LDSB(B_, QC_) do { \
  _Pragma("unroll") for (int j_ = 0; j_ < 2; ++j_) { \
  _Pragma("unroll") for (int ks_ = 0; ks_ < 2; ++ks_) { \
    const int row_ = wn + (QC_) * 32 + j_ * 16 + lm; \
    bf[j_][ks_] = *(const short8*)(lds_c + 65536 + (B_) * 32768 + row_ * 128 + ((((ks_ << 2) | qd) ^ sw) << 4)); } } } while (0)

#define G8_MFMA(QR_, QC_) do { \
  __builtin_amdgcn_s_setprio(1); \
  _Pragma("unroll") for (int ks_ = 0; ks_ < 2; ++ks_) { \
  _Pragma("unroll") for (int i_ = 0; i_ < 4; ++i_) { \
  _Pragma("unroll") for (int j_ = 0; j_ < 2; ++j_) { \
    acc[QR_][QC_][i_][j_] = __builtin_amdgcn_mfma_f32_16x16x32_bf16( \
        af[i_][ks_], bf[j_][ks_], acc[QR_][QC_][i_][j_], 0, 0, 0); } } } \
  __builtin_amdgcn_s_setprio(0); } while (0)

// stage one 128x64 half-tile (16 KB): 2 x global_load_lds(16B) per thread.
// LDS dest is linear; global source column pre-swizzled (rule #21 involution).
#define G8_STAGE(GP_, LB_, B_, H_, KT_) do { \
  _Pragma("unroll") for (int n_ = 0; n_ < 2; ++n_) { \
    const int c_   = n_ * 512 + tid; \
    const int row_ = (H_) * 128 + (c_ >> 3); \
    const int sl_  = (c_ & 7) ^ (row_ & 7); \
    __builtin_amdgcn_global_load_lds( \
      (const GLOBAL_AS void*)((GP_) + (long)row_ * K + (long)kbase + (long)(KT_) * 64 + sl_ * 8), \
      (LDS_AS void*)(lds_c + (LB_) + (B_) * 32768 + (H_) * 16384 + (n_ * 512 + (tid & 448)) * 16), \
      16, 0, 0); } } while (0)

template <typename OutT>
__global__ __launch_bounds__(512, 2) void gemm8p(
    const __hip_bfloat16* __restrict__ A, const __hip_bfloat16* __restrict__ Bt,
    OutT* __restrict__ C,
    int M, int N, int K,            // per-batch dims (K = full per-batch K)
    long sA, long sB, long sC, long sCsplit,
    int ksh, float scale)
{
    __shared__ char lds_c[131072];  // A: [0,64K) = 2 x 32KB bufs; B: [64K,128K)

    // ---- T1: bijective XCD swizzle of the linear block id ----
    const int gx = gridDim.x, gy = gridDim.y;
    const int nwg = gx * gy * gridDim.z;
    int lid = blockIdx.x + gx * (blockIdx.y + gy * blockIdx.z);
    lid = (lid & 7) * (nwg >> 3) + (lid >> 3);     // nwg % 8 == 0 at our grids
    const int bx = lid % gx;
    const int t1 = lid / gx;
    const int by = t1 % gy;
    const int bz = t1 / gy;

    const int batch = bz >> ksh;
    const int kh    = bz & ((1 << ksh) - 1);
    const int Kblk  = K >> ksh;
    const int kbase = kh * Kblk;
    const int NTK   = Kblk >> 6;                   // K-tiles (>= 2 required)

    const int m0 = bx * 256;
    const int n0 = by * 256;

    const int tid  = threadIdx.x;
    const int lane = tid & 63;
    const int lm   = lane & 15;
    const int qd   = lane >> 4;
    const int sw   = lm & 7;
    const int wid  = tid >> 6;
    const int wm   = (wid >> 2) * 128;             // wave m-offset (2 rows)
    const int wn   = (wid & 3) * 64;               // wave n-offset (4 cols)

    const short* Ag2 = (const short*)A + (long)batch * sA + (long)m0 * K;
    const short* Bg2 = (const short*)Bt + (long)batch * sB + (long)n0 * K;

    floatx4 acc[2][2][4][2] = {};
    short8 af[4][2];
    short8 bf[2][2];

    // ---- prologue: tile0 fully + B0(tile1); leave B0(1) in flight ----
    G8_STAGE(Bg2, 65536, 0, 0, 0);
    G8_STAGE(Bg2, 65536, 0, 1, 0);
    G8_STAGE(Ag2, 0,     0, 0, 0);
    G8_STAGE(Ag2, 0,     0, 1, 0);
    if (NTK > 1) {
        G8_STAGE(Bg2, 65536, 1, 0, 1);
        asm volatile("s_waitcnt vmcnt(2)" ::: "memory");
    } else {
        asm volatile("s_waitcnt vmcnt(0)" ::: "memory");
    }
    __builtin_amdgcn_s_barrier();

    for (int t = 0; t < NTK; ++t) {
        const int b  = t & 1;
        const int nb = b ^ 1;
        const bool st1 = (t + 1 < NTK);
        const bool st2 = (t + 2 < NTK);

        // ---- phase 1: quad (0,0) ----
        G8_LDSA(b, 0);
        G8_LDSB(b, 0);
        if (st1) G8_STAGE(Bg2, 65536, nb, 1, t + 1);
        __builtin_amdgcn_s_barrier();
        G8_MFMA(0, 0);
        if (st1) asm volatile("s_waitcnt vmcnt(4)" ::: "memory");
        else     asm volatile("s_waitcnt vmcnt(0)" ::: "memory");
        __builtin_amdgcn_s_barrier();

        // ---- phase 2: quad (1,0) ----
        G8_LDSA(b, 1);
        if (st1) G8_STAGE(Ag2, 0, nb, 0, t + 1);
        __builtin_amdgcn_s_barrier();
        G8_MFMA(1, 0);
        __builtin_amdgcn_s_barrier();

        // ---- phase 3: quad (1,1) ----
        G8_LDSB(b, 1);
        if (st1) G8_STAGE(Ag2, 0, nb, 1, t + 1);
        __builtin_amdgcn_s_barrier();
        G8_MFMA(1, 1);
        __builtin_amdgcn_s_barrier();

        // ---- phase 4: quad (0,1) (A0 re-read) ----
        G8_LDSA(b, 0);
        if (st2) G8_STAGE(Bg2, 65536, b, 0, t + 2);
        __builtin_amdgcn_s_barrier();
        G8_MFMA(0, 1);
        if (st2) asm volatile("s_waitcnt vmcnt(4)" ::: "memory");
        else     asm volatile("s_waitcnt vmcnt(2)" ::: "memory");
        __builtin_amdgcn_s_barrier();
    }

    // ---- epilogue: C/D layout col = lm(+16j...), row = qd*4+r ----
    OutT* Cg = C + (long)batch * sC + (long)kh * sCsplit;
#pragma unroll
    for (int qr = 0; qr < 2; ++qr)
#pragma unroll
    for (int i = 0; i < 4; ++i) {
        const int row0 = m0 + wm + qr * 64 + i * 16 + qd * 4;
#pragma unroll
        for (int qc = 0; qc < 2; ++qc)
#pragma unroll
        for (int j = 0; j < 2; ++j) {
            const int col = n0 + wn + qc * 32 + j * 16 + lm;
#pragma unroll
            for (int r = 0; r < 4; ++r)
                Cg[(long)(row0 + r) * N + col] = (OutT)(acc[qr][qc][i][j][r] * scale);
        }
    }
}

// ======================= fp32 -> bf16 converters ===========================
__global__ __launch_bounds__(256) void convert_bf16(
    const float* __restrict__ src, __hip_bfloat16* __restrict__ dst)
{
    const long g = ((long)blockIdx.x * 256 + threadIdx.x) * 4;
    const float4 v = *(const float4*)(src + g);
    bf4 o;
    o.v[0] = (__hip_bfloat16)v.x; o.v[1] = (__hip_bfloat16)v.y;
    o.v[2] = (__hip_bfloat16)v.z; o.v[3] = (__hip_bfloat16)v.w;
    *(bf4*)(dst + g) = o;
}

// 6 weights [256,256] -> contiguous bf16 slots of 65536
__global__ __launch_bounds__(256) void convert_w6(
    const float* w0, const float* w1, const float* w2,
    const float* w3, const float* w4, const float* w5,
    __hip_bfloat16* __restrict__ dst)
{
    const float* srcs[6] = {w0, w1, w2, w3, w4, w5};
    const float* s = srcs[blockIdx.y];
    const long off = (long)blockIdx.y * 65536;
    const long g = ((long)blockIdx.x * 256 + threadIdx.x) * 4;
    const float4 v = *(const float4*)(s + g);
    bf4 o;
    o.v[0] = (__hip_bfloat16)v.x; o.v[1] = (__hip_bfloat16)v.y;
    o.v[2] = (__hip_bfloat16)v.z; o.v[3] = (__hip_bfloat16)v.w;
    *(bf4*)(dst + off + g) = o;
}

// src [bz][R][C] fp32 -> dst [bz][C][R] bf16.  64(r) x 32(c) tiles; stores
// are bf2 (4B/lane, 128B wave segments) instead of the old 2B/lane.
__global__ __launch_bounds__(256) void transpose_to_bf16(
    const float* __restrict__ src, __hip_bfloat16* __restrict__ dst, int R, int C)
{
    __shared__ __hip_bfloat16 tt[32][66];
    const long bo = (long)blockIdx.z * R * C;
    const int tx = threadIdx.x & 31;
    const int ty = threadIdx.x >> 5;            // 0..7
    const int c0 = blockIdx.x * 32;
    const int r0 = blockIdx.y * 64;
#pragma unroll
    for (int p = 0; p < 8; ++p)
        tt[tx][p * 8 + ty] = (__hip_bfloat16)src[bo + (long)(r0 + p * 8 + ty) * C + c0 + tx];
    __syncthreads();
#pragma unroll
    for (int p = 0; p < 4; ++p) {
        const int c = p * 8 + ty;
        bf2 o;
        o.x = tt[c][2 * tx];
        o.y = tt[c][2 * tx + 1];
        *(bf2*)(dst + bo + (long)(c0 + c) * R + r0 + 2 * tx) = o;
    }
}

// ============================== entmax-1.5 =================================
// Register-resident: row of L = EPT*256 bf16 in EPT VGPRs/thread.
// z = Zin (+ log(max(Bias+Bias2,1e-6)) if HB; Bias2 = split-K partial).
template <int EPT, bool HB>
__global__ __launch_bounds__(256) void entmax_reg(
    const __hip_bfloat16* __restrict__ Zin, const float* __restrict__ Bias,
    const float* __restrict__ Bias2, __hip_bfloat16* __restrict__ Out)
{
    constexpr int L = EPT * 256;
    constexpr int NP = EPT / 2;
    __shared__ float rbuf[8];
    const int tid = threadIdx.x;
    const long base = (long)blockIdx.x * L;

    float z[EPT];
    float lmax = -3.4e38f;
    const unsigned short* Zp = (const unsigned short*)(Zin + base);
#pragma unroll
    for (int e = 0; e < NP; ++e) {
        const int idx = (tid + e * 256) * 2;
        const unsigned int u = *(const unsigned int*)(Zp + idx);
        float a = __uint_as_float(u << 16);
        float b = __uint_as_float(u & 0xffff0000u);
        if (HB) {
            const float2 bv = *(const float2*)(Bias + base + idx);
            const float2 b2 = *(const float2*)(Bias2 + base + idx);
            a += logf(fmaxf(bv.x + b2.x, 1e-6f));
            b += logf(fmaxf(bv.y + b2.y, 1e-6f));
        }
        z[2 * e] = a; z[2 * e + 1] = b;
        lmax = fmaxf(lmax, fmaxf(a, b));
    }
    for (int o = 32; o > 0; o >>= 1) lmax = fmaxf(lmax, __shfl_down(lmax, o));
    if ((tid & 63) == 0) rbuf[tid >> 6] = lmax;
    __syncthreads();
    const float mx = fmaxf(fmaxf(rbuf[0], rbuf[1]), fmaxf(rbuf[2], rbuf[3]));
#pragma unroll
    for (int e = 0; e < EPT; ++e) z[e] = (z[e] - mx) * 0.5f;

    float tau = -1.0f;
    for (int it = 0; it < 24; ++it) {
        float f = 0.f, g = 0.f;
#pragma unroll
        for (int e = 0; e < EPT; ++e) {
            const float d = fmaxf(z[e] - tau, 0.f);
            f = fmaf(d, d, f);
            g += d;
        }
        for (int o = 32; o > 0; o >>= 1) {
            f += __shfl_down(f, o);
            g += __shfl_down(g, o);
        }
        __syncthreads();
        if ((tid & 63) == 0) {
            rbuf[(tid >> 6) * 2] = f;
            rbuf[(tid >> 6) * 2 + 1] = g;
        }
        __syncthreads();
        f = rbuf[0] + rbuf[2] + rbuf[4] + rbuf[6];
        g = rbuf[1] + rbuf[3] + rbuf[5] + rbuf[7];
        if (g <= 0.f) break;
        const float step = (f - 1.0f) / (2.0f * g);
        tau += step;
        if (!(fabsf(step) > 1e-7f)) break;
    }

#pragma unroll
    for (int e = 0; e < NP; ++e) {
        const int idx = (tid + e * 256) * 2;
        const float d0 = fmaxf(z[2 * e] - tau, 0.f);
        const float d1 = fmaxf(z[2 * e + 1] - tau, 0.f);
        bf2 o;
        o.x = (__hip_bfloat16)(d0 * d0);
        o.y = (__hip_bfloat16)(d1 * d1);
        *(bf2*)(Out + base + idx) = o;
    }
}

// ===================== out0 = xfo + LayerNorm(xf) ==========================
__global__ __launch_bounds__(256) void ln_add_kernel(
    const float* __restrict__ xf, const float* __restrict__ gam,
    const float* __restrict__ bet, const float* __restrict__ xfo,
    float* __restrict__ out0)
{
    __shared__ float rbuf[4];
    const int tid = threadIdx.x;
    const long base = (long)blockIdx.x * 256;
    const float x = xf[base + tid];

    float s = x;
    for (int o = 32; o > 0; o >>= 1) s += __shfl_down(s, o);
    if ((tid & 63) == 0) rbuf[tid >> 6] = s;
    __syncthreads();
    const float mu = (rbuf[0] + rbuf[1] + rbuf[2] + rbuf[3]) * (1.0f / 256.0f);
    const float d = x - mu;

    float v = d * d;
    for (int o = 32; o > 0; o >>= 1) v += __shfl_down(v, o);
    __syncthreads();
    if ((tid & 63) == 0) rbuf[tid >> 6] = v;
    __syncthreads();
    const float var = (rbuf[0] + rbuf[1] + rbuf[2] + rbuf[3]) * (1.0f / 256.0f);

    const float ln = d * rsqrtf(var + 1e-5f) * gam[tid] + bet[tid];
    out0[base + tid] = xfo[base + tid] + ln;
}

// ================================ driver ===================================
extern "C" void kernel_launch(void* const* d_in, const int* in_sizes, int n_in,
                              void* d_out, int out_size, void* d_ws, size_t ws_size,
                              hipStream_t stream)
{
    (void)in_sizes; (void)n_in; (void)out_size; (void)ws_size;

    const float* xs      = (const float*)d_in[0];
    const float* xf      = (const float*)d_in[1];
    const float* xs_fine = (const float*)d_in[2];
    const float* S_s     = (const float*)d_in[4];
    const float* cfa_wq  = (const float*)d_in[6];
    const float* cfa_bq  = (const float*)d_in[7];
    const float* cfa_wk  = (const float*)d_in[8];
    const float* cfa_bk  = (const float*)d_in[9];
    const float* wqs     = (const float*)d_in[14];
    const float* bqs     = (const float*)d_in[15];
    const float* wkf     = (const float*)d_in[16];
    const float* bkf     = (const float*)d_in[17];
    const float* wvs     = (const float*)d_in[18];
    const float* bvs     = (const float*)d_in[19];
    const float* wof     = (const float*)d_in[24];
    const float* bof     = (const float*)d_in[25];
    const float* fn_g    = (const float*)d_in[28];
    const float* fn_b    = (const float*)d_in[29];

    // ---- workspace layout (MB offsets; peak ~221 MB, 224 MiB proven) ----
    char* w = (char*)d_ws;
    __hip_bfloat16* Sb   = (__hip_bfloat16*)(w);                   // 64 MB
    __hip_bfloat16* xsfb = (__hip_bfloat16*)(w);                   // 16 MB (dead before Sb written)
    __hip_bfloat16* SsTb = (__hip_bfloat16*)(w + (64ll  << 20));   // 64 MB
    __hip_bfloat16* AfTb = (__hip_bfloat16*)(w + (64ll  << 20));   // 16 MB (after BT gemm)
    float*          BT   = (float*)         (w + (128ll << 20));   // 32 MB (split-K partial 0)
    __hip_bfloat16* CMT  = (__hip_bfloat16*)(w + (160ll << 20));   // 16 MB
    float*          BT1  = (float*)         (w + (176ll << 20));   // 32 MB partial 1 (over dead Kfb/Qfb/Qb/Kmb)
    __hip_bfloat16* Kfb  = (__hip_bfloat16*)(w + (176ll << 20));   // 16 MB (dead before BT1 written)
    __hip_bfloat16* Qfb  = (__hip_bfloat16*)(w + (192ll << 20));   //  4 MB (dead before BT1)
    __hip_bfloat16* Qb   = (__hip_bfloat16*)(w + (196ll << 20));   //  4 MB (dead before BT1)
    __hip_bfloat16* T1b  = Qb;                                     //  (after entmax4 consumed BT1)
    __hip_bfloat16* Kmb  = (__hip_bfloat16*)(w + (200ll << 20));   //  4 MB (dead before BT1)
    __hip_bfloat16* xsb  = (__hip_bfloat16*)(w + (208ll << 20));   //  4 MB
    __hip_bfloat16* xfb  = (__hip_bfloat16*)(w + (212ll << 20));   //  4 MB
    __hip_bfloat16* wb   = (__hip_bfloat16*)(w + (216ll << 20));   //  0.75 MB
    __hip_bfloat16* VsTb = (__hip_bfloat16*)(w + (217ll << 20));   //  4 MB (moved out of BT1 range)
    __hip_bfloat16* wqs_b = wb;
    __hip_bfloat16* wkf_b = wb + 65536;
    __hip_bfloat16* wvs_b = wb + 131072;
    __hip_bfloat16* cwq_b = wb + 196608;
    __hip_bfloat16* cwk_b = wb + 262144;
    __hip_bfloat16* wof_b = wb + 327680;

    float* out0 = (float*)d_out;
    float* out1 = out0 + 2097152;
    float* outC = out0 + 4194304;

    const dim3 blk(256);
    const dim3 blk8(512);

    // ---- conversions ----
    convert_bf16<<<dim3(2048), blk, 0, stream>>>(xs, xsb);
    convert_bf16<<<dim3(2048), blk, 0, stream>>>(xf, xfb);
    convert_bf16<<<dim3(8192), blk, 0, stream>>>(xs_fine, xsfb);
    convert_w6<<<dim3(64, 6), blk, 0, stream>>>(wqs, wkf, wvs, cfa_wq, cfa_wk, wof, wb);
    // S_s [8,4096,1024] fp32 -> SsTb [8,1024,4096] bf16
    transpose_to_bf16<<<dim3(32, 64, 8), blk, 0, stream>>>(S_s, SsTb, 4096, 1024);

    // ---- linears (MFMA): Y = X @ W^T + b ----
    mfma_gemm<__hip_bfloat16><<<dim3(64, 2, 1), blk, 0, stream>>>(xsb, wqs_b, bqs,
        Qb, nullptr, 8192, 256, 256, 0, 0, 0, 0, 1024, 1.f);
    mfma_gemm<__hip_bfloat16><<<dim3(64, 2, 1), blk, 0, stream>>>(xfb, wkf_b, bkf,
        Kmb, nullptr, 8192, 256, 256, 0, 0, 0, 0, 1024, 1.f);
    mfma_gemm<float><<<dim3(64, 2, 1), blk, 0, stream>>>(xsb, wvs_b, bvs,
        (float*)nullptr, VsTb, 8192, 256, 256, 0, 0, 0, 0, 1024, 1.f);  // Vs^T per batch
    mfma_gemm<__hip_bfloat16><<<dim3(64, 2, 1), blk, 0, stream>>>(xfb, cwq_b, cfa_bq,
        Qfb, nullptr, 8192, 256, 256, 0, 0, 0, 0, 1024, 1.f);
    mfma_gemm<__hip_bfloat16><<<dim3(256, 2, 1), blk, 0, stream>>>(xsfb, cwk_b, cfa_bk,
        Kfb, nullptr, 32768, 256, 256, 0, 0, 0, 0, 1024, 1.f);

    // ---- C_M = Q Km^T / 16 -> out[2] fp32 + CMT bf16 (per-batch transposed) ----
    mfma_gemm<float><<<dim3(8, 8, 8), blk, 0, stream>>>(Qb, Kmb, nullptr,
        outC, CMT, 1024, 1024, 256, 262144, 262144, 1048576, 1048576, 1024, 0.0625f);

    // ---- scores = Qf Kf^T / 16 -> Sb bf16 [8,1024,4096] (8-phase GEMM) ----
    gemm8p<__hip_bfloat16><<<dim3(4, 16, 8), blk8, 0, stream>>>(Qfb, Kfb, Sb,
        1024, 4096, 256, 262144, 1048576, 4194304, 0, 0, 0.0625f);

    // ---- P = entmax15 rows (in place) ----
    entmax_reg<16, false><<<dim3(8192), blk, 0, stream>>>(Sb, nullptr, nullptr, Sb);

    // ---- BT = P @ S_s (== bias_F^T) fp32, split-K x2 partials ----
    gemm8p<float><<<dim3(4, 4, 16), blk8, 0, stream>>>(Sb, SsTb, BT,
        1024, 1024, 4096, 4194304, 4194304, 1048576, 12582912, 1, 1.f);

    // ---- AfT = entmax15(CMT + log(max(BT0+BT1,eps))) rows -> bf16 ----
    entmax_reg<4, true><<<dim3(8192), blk, 0, stream>>>(CMT, BT, BT1, AfTb);

    // ---- T1 = AfT @ Vs -> bf16 ----
    mfma_gemm<__hip_bfloat16><<<dim3(8, 2, 8), blk, 0, stream>>>(AfTb, VsTb, nullptr,
        T1b, nullptr, 1024, 256, 1024, 1048576, 262144, 262144, 0, 1024, 1.f);

    // ---- out1 = T1 @ wof^T + bof ----
    mfma_gemm<float><<<dim3(64, 2, 1), blk, 0, stream>>>(T1b, wof_b, bof,
        out1, nullptr, 8192, 256, 256, 0, 0, 0, 0, 1024, 1.f);

    // ---- out0 = out1 + LayerNorm(xf) ----
    ln_add_kernel<<<dim3(8192), blk, 0, stream>>>(xf, fn_g, fn_b, out1, out0);
}

// Round 2
// 635.000 us; speedup vs baseline: 1.2357x; 1.1264x over previous
//
#include <hip/hip_runtime.h>
#include <hip/hip_bf16.h>

// ---------------------------------------------------------------------------
// Hie_Couple live subgraph (xs_/A_s/C_M_S/bias_S/Vf dead in reference).
// All GEMMs on bf16 MFMA. entmax-1.5 via per-wave register-resident
// active-set exact solver (this round; was block-wide Newton x24).
// ---------------------------------------------------------------------------

typedef __attribute__((ext_vector_type(8))) short short8;
typedef __attribute__((ext_vector_type(4))) float floatx4;

#define GLOBAL_AS __attribute__((address_space(1)))
#define LDS_AS    __attribute__((address_space(3)))

struct alignas(4) bf2 { __hip_bfloat16 x, y; };
struct alignas(8) bf4 { __hip_bfloat16 v[4]; };

// ============================ bf16 MFMA GEMM ===============================
// (legacy 128x128 kernel, kept for the small linears / C_M / T1 / out1)
// C[M,N] = scale * A[M,K] @ Bt[N,K]^T (+ bias[col]); strides per blockIdx.z.
// Optional CT: bf16, per-RB-row-group transposed.
#define MT 128
#define NT 128
#define KT 64

template <typename OutT>
__global__ __launch_bounds__(256) void mfma_gemm(
    const __hip_bfloat16* __restrict__ A, const __hip_bfloat16* __restrict__ Bt,
    const float* __restrict__ bias, OutT* __restrict__ C,
    __hip_bfloat16* __restrict__ CT,
    int M, int N, int K,
    long sA, long sB, long sC, long sCT, int RB, float scale)
{
    __shared__ __hip_bfloat16 Asm[MT * KT];  // 16 KB
    __shared__ __hip_bfloat16 Bsm[NT * KT];  // 16 KB

    const int bz = blockIdx.z;
    const short* Ag = (const short*)(A + (long)bz * sA);
    const short* Bg = (const short*)(Bt + (long)bz * sB);

    const int m0 = blockIdx.x * MT;
    const int n0 = blockIdx.y * NT;

    const int tid  = threadIdx.x;
    const int lane = tid & 63;
    const int wm   = (tid >> 6 & 1) * 64;   // wave m-offset
    const int wn   = (tid >> 7) * 64;       // wave n-offset
    const int lm   = lane & 15;
    const int quad = lane >> 4;

    floatx4 acc[4][4] = {};

    for (int k0 = 0; k0 < K; k0 += KT) {
#pragma unroll
        for (int p = 0; p < 4; ++p) {
            const int idx = p * 256 + tid;
            const int row = idx >> 3;
            const int c8  = idx & 7;
            const int wbase = (p * 256 + (tid & 192)) * 16;  // wave-uniform base
            __builtin_amdgcn_global_load_lds(
                (const GLOBAL_AS void*)(Ag + (long)(m0 + row) * K + k0 + c8 * 8),
                (LDS_AS void*)((char*)Asm + wbase), 16, 0, 0);
            __builtin_amdgcn_global_load_lds(
                (const GLOBAL_AS void*)(Bg + (long)(n0 + row) * K + k0 + c8 * 8),
                (LDS_AS void*)((char*)Bsm + wbase), 16, 0, 0);
        }
        __syncthreads();

#pragma unroll
        for (int ks = 0; ks < KT / 32; ++ks) {
            short8 af[4], bf[4];
#pragma unroll
            for (int i = 0; i < 4; ++i) {
                af[i] = *(const short8*)((const short*)Asm + (wm + i * 16 + lm) * KT + ks * 32 + quad * 8);
                bf[i] = *(const short8*)((const short*)Bsm + (wn + i * 16 + lm) * KT + ks * 32 + quad * 8);
            }
#pragma unroll
            for (int i = 0; i < 4; ++i)
#pragma unroll
                for (int j = 0; j < 4; ++j)
                    acc[i][j] = __builtin_amdgcn_mfma_f32_16x16x32_bf16(af[i], bf[j], acc[i][j], 0, 0, 0);
        }
        __syncthreads();
    }

    float bb[4] = {0.f, 0.f, 0.f, 0.f};
    if (bias) {
#pragma unroll
        for (int j = 0; j < 4; ++j) bb[j] = bias[n0 + wn + lm + j * 16];
    }
    OutT* Cg = C ? C + (long)bz * sC : nullptr;
    __hip_bfloat16* CTg = CT ? CT + (long)bz * sCT : nullptr;

#pragma unroll
    for (int i = 0; i < 4; ++i) {
        const int row0 = m0 + wm + i * 16 + quad * 4;
#pragma unroll
        for (int j = 0; j < 4; ++j) {
            const int col = n0 + wn + lm + j * 16;
            float v[4];
#pragma unroll
            for (int r = 0; r < 4; ++r) v[r] = acc[i][j][r] * scale + bb[j];
            if (Cg) {
#pragma unroll
                for (int r = 0; r < 4; ++r)
                    Cg[(long)(row0 + r) * N + col] = (OutT)v[r];
            }
            if (CTg) {
                bf4 pk;
#pragma unroll
                for (int r = 0; r < 4; ++r) pk.v[r] = (__hip_bfloat16)v[r];
                const long b_i = row0 / RB, r_i = row0 % RB;
                *(bf4*)(CTg + b_i * (long)N * RB + (long)col * RB + r_i) = pk;
            }
        }
    }
}

// ======================= 256x256 8-phase MFMA GEMM =========================
// C[M,N] = scale * A[M,K']@Bt[N,K']^T, per-batch strides, optional split-K:
// blockIdx.z = batch*(1<<ksh) + kh; each block does K/(1<<ksh) of the K dim,
// writing its partial to C + batch*sC + kh*sCsplit.
// 512 threads = 8 waves (2M x 4N), per-wave 128x64 output (acc[2][2][4][2]).
// BK=64; LDS 128 KB (A,B x 2 buffers); 4 phases/K-tile x 16 MFMA.
// T2: slot ^= (row&7) swizzle (inverse-swizzled global src, swizzled ds_read).
// T3/T4: one half-tile staged per phase, counted vmcnt (never 0 mid-loop).
// T5: setprio around each MFMA cluster.  T1: XCD-bijective block swizzle.
//
// Stage schedule (tile t computed from buf b=t&1, nb=b^1):
//   ph1 reads A0,B0(t) | stages B1(t+1)->nb | vmcnt(4) guarantees A1(t)
//   ph2 reads A1(t)    | stages A0(t+1)->nb
//   ph3 reads B1(t)    | stages A1(t+1)->nb
//   ph4 re-reads A0(t) | stages B0(t+2)->b  | vmcnt(4) guarantees B0,B1,A0(t+1)
// Every staged region's last reader finished >=1 barrier before the issue.

#define G8_LDSA(B_, QR_) do { \
  _Pragma("unroll") for (int i_ = 0; i_ < 4; ++i_) { \
  _Pragma("unroll") for (int ks_ = 0; ks_ < 2; ++ks_) { \
    const int row_ = wm + (QR_) * 64 + i_ * 16 + lm; \
    af[i_][ks_] = *(const short8*)(lds_c + (B_) * 32768 + row_ * 128 + ((((ks_ << 2) | qd) ^ sw) << 4)); } } } while (0)

#define G8_LDSB(B_, QC_) do { \
  _Pragma("unroll") for (int j_ = 0; j_ < 2; ++j_) { \
  _Pragma("unroll") for (int ks_ = 0; ks_ < 2; ++ks_) { \
    const int row_ = wn + (QC_) * 32 + j_ * 16 + lm; \
    bf[j_][ks_] = *(const short8*)(lds_c + 65536 + (B_) * 32768 + row_ * 128 + ((((ks_ << 2) | qd) ^ sw) << 4)); } } } while (0)

#define G8_MFMA(QR_, QC_) do { \
  __builtin_amdgcn_s_setprio(1); \
  _Pragma("unroll") for (int ks_ = 0; ks_ < 2; ++ks_) { \
  _Pragma("unroll") for (int i_ = 0; i_ < 4; ++i_) { \
  _Pragma("unroll") for (int j_ = 0; j_ < 2; ++j_) { \
    acc[QR_][QC_][i_][j_] = __builtin_amdgcn_mfma_f32_16x16x32_bf16( \
        af[i_][ks_], bf[j_][ks_], acc[QR_][QC_][i_][j_], 0, 0, 0); } } } \
  __builtin_amdgcn_s_setprio(0); } while (0)

// stage one 128x64 half-tile (16 KB): 2 x global_load_lds(16B) per thread.
// LDS dest is linear; global source column pre-swizzled (rule #21 involution).
#define G8_STAGE(GP_, LB_, B_, H_, KT_) do { \
  _Pragma("unroll") for (int n_ = 0; n_ < 2; ++n_) { \
    const int c_   = n_ * 512 + tid; \
    const int row_ = (H_) * 128 + (c_ >> 3); \
    const int sl_  = (c_ & 7) ^ (row_ & 7); \
    __builtin_amdgcn_global_load_lds( \
      (const GLOBAL_AS void*)((GP_) + (long)row_ * K + (long)kbase + (long)(KT_) * 64 + sl_ * 8), \
      (LDS_AS void*)(lds_c + (LB_) + (B_) * 32768 + (H_) * 16384 + (n_ * 512 + (tid & 448)) * 16), \
      16, 0, 0); } } while (0)

template <typename OutT>
__global__ __launch_bounds__(512, 2) void gemm8p(
    const __hip_bfloat16* __restrict__ A, const __hip_bfloat16* __restrict__ Bt,
    OutT* __restrict__ C,
    int M, int N, int K,            // per-batch dims (K = full per-batch K)
    long sA, long sB, long sC, long sCsplit,
    int ksh, float scale)
{
    __shared__ char lds_c[131072];  // A: [0,64K) = 2 x 32KB bufs; B: [64K,128K)

    // ---- T1: bijective XCD swizzle of the linear block id ----
    const int gx = gridDim.x, gy = gridDim.y;
    const int nwg = gx * gy * gridDim.z;
    int lid = blockIdx.x + gx * (blockIdx.y + gy * blockIdx.z);
    lid = (lid & 7) * (nwg >> 3) + (lid >> 3);     // nwg % 8 == 0 at our grids
    const int bx = lid % gx;
    const int t1 = lid / gx;
    const int by = t1 % gy;
    const int bz = t1 / gy;

    const int batch = bz >> ksh;
    const int kh    = bz & ((1 << ksh) - 1);
    const int Kblk  = K >> ksh;
    const int kbase = kh * Kblk;
    const int NTK   = Kblk >> 6;                   // K-tiles (>= 2 required)

    const int m0 = bx * 256;
    const int n0 = by * 256;

    const int tid  = threadIdx.x;
    const int lane = tid & 63;
    const int lm   = lane & 15;
    const int qd   = lane >> 4;
    const int sw   = lm & 7;
    const int wid  = tid >> 6;
    const int wm   = (wid >> 2) * 128;             // wave m-offset (2 rows)
    const int wn   = (wid & 3) * 64;               // wave n-offset (4 cols)

    const short* Ag2 = (const short*)A + (long)batch * sA + (long)m0 * K;
    const short* Bg2 = (const short*)Bt + (long)batch * sB + (long)n0 * K;

    floatx4 acc[2][2][4][2] = {};
    short8 af[4][2];
    short8 bf[2][2];

    // ---- prologue: tile0 fully + B0(tile1); leave B0(1) in flight ----
    G8_STAGE(Bg2, 65536, 0, 0, 0);
    G8_STAGE(Bg2, 65536, 0, 1, 0);
    G8_STAGE(Ag2, 0,     0, 0, 0);
    G8_STAGE(Ag2, 0,     0, 1, 0);
    if (NTK > 1) {
        G8_STAGE(Bg2, 65536, 1, 0, 1);
        asm volatile("s_waitcnt vmcnt(2)" ::: "memory");
    } else {
        asm volatile("s_waitcnt vmcnt(0)" ::: "memory");
    }
    __builtin_amdgcn_s_barrier();

    for (int t = 0; t < NTK; ++t) {
        const int b  = t & 1;
        const int nb = b ^ 1;
        const bool st1 = (t + 1 < NTK);
        const bool st2 = (t + 2 < NTK);

        // ---- phase 1: quad (0,0) ----
        G8_LDSA(b, 0);
        G8_LDSB(b, 0);
        if (st1) G8_STAGE(Bg2, 65536, nb, 1, t + 1);
        __builtin_amdgcn_s_barrier();
        G8_MFMA(0, 0);
        if (st1) asm volatile("s_waitcnt vmcnt(4)" ::: "memory");
        else     asm volatile("s_waitcnt vmcnt(0)" ::: "memory");
        __builtin_amdgcn_s_barrier();

        // ---- phase 2: quad (1,0) ----
        G8_LDSA(b, 1);
        if (st1) G8_STAGE(Ag2, 0, nb, 0, t + 1);
        __builtin_amdgcn_s_barrier();
        G8_MFMA(1, 0);
        __builtin_amdgcn_s_barrier();

        // ---- phase 3: quad (1,1) ----
        G8_LDSB(b, 1);
        if (st1) G8_STAGE(Ag2, 0, nb, 1, t + 1);
        __builtin_amdgcn_s_barrier();
        G8_MFMA(1, 1);
        __builtin_amdgcn_s_barrier();

        // ---- phase 4: quad (0,1) (A0 re-read) ----
        G8_LDSA(b, 0);
        if (st2) G8_STAGE(Bg2, 65536, b, 0, t + 2);
        __builtin_amdgcn_s_barrier();
        G8_MFMA(0, 1);
        if (st2) asm volatile("s_waitcnt vmcnt(4)" ::: "memory");
        else     asm volatile("s_waitcnt vmcnt(2)" ::: "memory");
        __builtin_amdgcn_s_barrier();
    }

    // ---- epilogue: C/D layout col = lm(+16j...), row = qd*4+r ----
    OutT* Cg = C + (long)batch * sC + (long)kh * sCsplit;
#pragma unroll
    for (int qr = 0; qr < 2; ++qr)
#pragma unroll
    for (int i = 0; i < 4; ++i) {
        const int row0 = m0 + wm + qr * 64 + i * 16 + qd * 4;
#pragma unroll
        for (int qc = 0; qc < 2; ++qc)
#pragma unroll
        for (int j = 0; j < 2; ++j) {
            const int col = n0 + wn + qc * 32 + j * 16 + lm;
#pragma unroll
            for (int r = 0; r < 4; ++r)
                Cg[(long)(row0 + r) * N + col] = (OutT)(acc[qr][qc][i][j][r] * scale);
        }
    }
}

// ======================= fp32 -> bf16 converters ===========================
__global__ __launch_bounds__(256) void convert_bf16(
    const float* __restrict__ src, __hip_bfloat16* __restrict__ dst)
{
    const long g = ((long)blockIdx.x * 256 + threadIdx.x) * 4;
    const float4 v = *(const float4*)(src + g);
    bf4 o;
    o.v[0] = (__hip_bfloat16)v.x; o.v[1] = (__hip_bfloat16)v.y;
    o.v[2] = (__hip_bfloat16)v.z; o.v[3] = (__hip_bfloat16)v.w;
    *(bf4*)(dst + g) = o;
}

// 6 weights [256,256] -> contiguous bf16 slots of 65536
__global__ __launch_bounds__(256) void convert_w6(
    const float* w0, const float* w1, const float* w2,
    const float* w3, const float* w4, const float* w5,
    __hip_bfloat16* __restrict__ dst)
{
    const float* srcs[6] = {w0, w1, w2, w3, w4, w5};
    const float* s = srcs[blockIdx.y];
    const long off = (long)blockIdx.y * 65536;
    const long g = ((long)blockIdx.x * 256 + threadIdx.x) * 4;
    const float4 v = *(const float4*)(s + g);
    bf4 o;
    o.v[0] = (__hip_bfloat16)v.x; o.v[1] = (__hip_bfloat16)v.y;
    o.v[2] = (__hip_bfloat16)v.z; o.v[3] = (__hip_bfloat16)v.w;
    *(bf4*)(dst + off + g) = o;
}

// src [bz][R][C] fp32 -> dst [bz][C][R] bf16.  64(r) x 32(c) tiles; stores
// are bf2 (4B/lane, 128B wave segments).
__global__ __launch_bounds__(256) void transpose_to_bf16(
    const float* __restrict__ src, __hip_bfloat16* __restrict__ dst, int R, int C)
{
    __shared__ __hip_bfloat16 tt[32][66];
    const long bo = (long)blockIdx.z * R * C;
    const int tx = threadIdx.x & 31;
    const int ty = threadIdx.x >> 5;            // 0..7
    const int c0 = blockIdx.x * 32;
    const int r0 = blockIdx.y * 64;
#pragma unroll
    for (int p = 0; p < 8; ++p)
        tt[tx][p * 8 + ty] = (__hip_bfloat16)src[bo + (long)(r0 + p * 8 + ty) * C + c0 + tx];
    __syncthreads();
#pragma unroll
    for (int p = 0; p < 4; ++p) {
        const int c = p * 8 + ty;
        bf2 o;
        o.x = tt[c][2 * tx];
        o.y = tt[c][2 * tx + 1];
        *(bf2*)(dst + bo + (long)(c0 + c) * R + r0 + 2 * tx) = o;
    }
}

// ============================== entmax-1.5 =================================
// Per-wave: one row of L = EPW*64 bf16 per 64-lane wave (EPW f32 VGPRs/lane).
// No barriers, no LDS; all reductions are 6-level __shfl_xor butterflies.
// z = Zin (+ log(max(Bias+Bias2,1e-6)) if HB; Bias2 = split-K partial).
// Solver: active-set exact solve. Given tau, active = {z > tau}; solve
// sum_{active}(z - tau')^2 = 1 in closed form (shifted: u = z - tau,
// k d^2 - 2 s1 d + (s2 - 1) = 0, d = (s1 - sqrt(s1^2 - k(s2-1)))/k).
// Any fixed point satisfies the true relu equation exactly; disc<0 clamps
// to a mean-shift step. 12 iters cap + 2 monotone Newton polish steps.
template <int EPW, bool HB>
__global__ __launch_bounds__(256) void entmax_wave(
    const __hip_bfloat16* __restrict__ Zin, const float* __restrict__ Bias,
    const float* __restrict__ Bias2, __hip_bfloat16* __restrict__ Out)
{
    constexpr int L = EPW * 64;
    constexpr int NC = EPW / 8;             // 16B chunks per lane
    const int lane = threadIdx.x & 63;
    const int wid  = threadIdx.x >> 6;
    const long base = ((long)blockIdx.x * 4 + wid) * (long)L;

    const short8* Zp = (const short8*)(Zin + base);
    float z[EPW];
    float lmax = -3.4e38f;
#pragma unroll
    for (int c = 0; c < NC; ++c) {
        const int e0  = c * 8;
        const int idx = (c * 64 + lane) * 8;     // element index within row
        const short8 u = Zp[c * 64 + lane];
        float bb[8];
        if (HB) {
            const float4 b0 = *(const float4*)(Bias  + base + idx);
            const float4 b4 = *(const float4*)(Bias  + base + idx + 4);
            const float4 c0 = *(const float4*)(Bias2 + base + idx);
            const float4 c4 = *(const float4*)(Bias2 + base + idx + 4);
            bb[0] = b0.x + c0.x; bb[1] = b0.y + c0.y;
            bb[2] = b0.z + c0.z; bb[3] = b0.w + c0.w;
            bb[4] = b4.x + c4.x; bb[5] = b4.y + c4.y;
            bb[6] = b4.z + c4.z; bb[7] = b4.w + c4.w;
        }
#pragma unroll
        for (int q = 0; q < 8; ++q) {
            float v = __uint_as_float(((unsigned)(unsigned short)u[q]) << 16);
            if (HB) v += logf(fmaxf(bb[q], 1e-6f));
            z[e0 + q] = v;
            lmax = fmaxf(lmax, v);
        }
    }
    for (int o = 32; o > 0; o >>= 1) lmax = fmaxf(lmax, __shfl_xor(lmax, o));
#pragma unroll
    for (int e = 0; e < EPW; ++e) z[e] = (z[e] - lmax) * 0.5f;

    // active-set exact-solve iterations (fixed point == exact solution)
    float tau = -1.0f;
    for (int it = 0; it < 12; ++it) {
        float s1 = 0.f, s2 = 0.f, kf = 0.f;
#pragma unroll
        for (int e = 0; e < EPW; ++e) {
            const float d = fmaxf(z[e] - tau, 0.f);
            s2 = fmaf(d, d, s2);
            s1 += d;
            kf += (d > 0.f) ? 1.f : 0.f;
        }
        for (int o = 32; o > 0; o >>= 1) {
            s1 += __shfl_xor(s1, o);
            s2 += __shfl_xor(s2, o);
            kf += __shfl_xor(kf, o);
        }
        if (kf < 0.5f) break;                    // degenerate guard
        const float disc  = fmaxf(fmaf(s1, s1, -kf * (s2 - 1.f)), 0.f);
        const float delta = (s1 - sqrtf(disc)) / kf;
        tau += delta;
        if (!(fabsf(delta) > 2e-6f)) break;
    }
    // Newton polish (monotone near root; no-op if already converged)
#pragma unroll
    for (int it = 0; it < 2; ++it) {
        float f = 0.f, g = 0.f;
#pragma unroll
        for (int e = 0; e < EPW; ++e) {
            const float d = fmaxf(z[e] - tau, 0.f);
            f = fmaf(d, d, f);
            g += d;
        }
        for (int o = 32; o > 0; o >>= 1) {
            f += __shfl_xor(f, o);
            g += __shfl_xor(g, o);
        }
        if (g > 0.f) tau += (f - 1.0f) / (2.0f * g);
    }

#pragma unroll
    for (int c = 0; c < NC; ++c) {
        const int e0 = c * 8;
        union { short8 s; __hip_bfloat16 h[8]; } o;
#pragma unroll
        for (int q = 0; q < 8; ++q) {
            const float d = fmaxf(z[e0 + q] - tau, 0.f);
            o.h[q] = (__hip_bfloat16)(d * d);
        }
        *((short8*)(Out + base) + c * 64 + lane) = o.s;
    }
}

// ===================== out0 = xfo + LayerNorm(xf) ==========================
__global__ __launch_bounds__(256) void ln_add_kernel(
    const float* __restrict__ xf, const float* __restrict__ gam,
    const float* __restrict__ bet, const float* __restrict__ xfo,
    float* __restrict__ out0)
{
    __shared__ float rbuf[4];
    const int tid = threadIdx.x;
    const long base = (long)blockIdx.x * 256;
    const float x = xf[base + tid];

    float s = x;
    for (int o = 32; o > 0; o >>= 1) s += __shfl_down(s, o);
    if ((tid & 63) == 0) rbuf[tid >> 6] = s;
    __syncthreads();
    const float mu = (rbuf[0] + rbuf[1] + rbuf[2] + rbuf[3]) * (1.0f / 256.0f);
    const float d = x - mu;

    float v = d * d;
    for (int o = 32; o > 0; o >>= 1) v += __shfl_down(v, o);
    __syncthreads();
    if ((tid & 63) == 0) rbuf[tid >> 6] = v;
    __syncthreads();
    const float var = (rbuf[0] + rbuf[1] + rbuf[2] + rbuf[3]) * (1.0f / 256.0f);

    const float ln = d * rsqrtf(var + 1e-5f) * gam[tid] + bet[tid];
    out0[base + tid] = xfo[base + tid] + ln;
}

// ================================ driver ===================================
extern "C" void kernel_launch(void* const* d_in, const int* in_sizes, int n_in,
                              void* d_out, int out_size, void* d_ws, size_t ws_size,
                              hipStream_t stream)
{
    (void)in_sizes; (void)n_in; (void)out_size; (void)ws_size;

    const float* xs      = (const float*)d_in[0];
    const float* xf      = (const float*)d_in[1];
    const float* xs_fine = (const float*)d_in[2];
    const float* S_s     = (const float*)d_in[4];
    const float* cfa_wq  = (const float*)d_in[6];
    const float* cfa_bq  = (const float*)d_in[7];
    const float* cfa_wk  = (const float*)d_in[8];
    const float* cfa_bk  = (const float*)d_in[9];
    const float* wqs     = (const float*)d_in[14];
    const float* bqs     = (const float*)d_in[15];
    const float* wkf     = (const float*)d_in[16];
    const float* bkf     = (const float*)d_in[17];
    const float* wvs     = (const float*)d_in[18];
    const float* bvs     = (const float*)d_in[19];
    const float* wof     = (const float*)d_in[24];
    const float* bof     = (const float*)d_in[25];
    const float* fn_g    = (const float*)d_in[28];
    const float* fn_b    = (const float*)d_in[29];

    // ---- workspace layout (MB offsets; peak ~221 MB, 224 MiB proven) ----
    char* w = (char*)d_ws;
    __hip_bfloat16* Sb   = (__hip_bfloat16*)(w);                   // 64 MB
    __hip_bfloat16* xsfb = (__hip_bfloat16*)(w);                   // 16 MB (dead before Sb written)
    __hip_bfloat16* SsTb = (__hip_bfloat16*)(w + (64ll  << 20));   // 64 MB
    __hip_bfloat16* AfTb = (__hip_bfloat16*)(w + (64ll  << 20));   // 16 MB (after BT gemm)
    float*          BT   = (float*)         (w + (128ll << 20));   // 32 MB (split-K partial 0)
    __hip_bfloat16* CMT  = (__hip_bfloat16*)(w + (160ll << 20));   // 16 MB
    float*          BT1  = (float*)         (w + (176ll << 20));   // 32 MB partial 1 (over dead Kfb/Qfb/Qb/Kmb)
    __hip_bfloat16* Kfb  = (__hip_bfloat16*)(w + (176ll << 20));   // 16 MB (dead before BT1 written)
    __hip_bfloat16* Qfb  = (__hip_bfloat16*)(w + (192ll << 20));   //  4 MB (dead before BT1)
    __hip_bfloat16* Qb   = (__hip_bfloat16*)(w + (196ll << 20));   //  4 MB (dead before BT1)
    __hip_bfloat16* T1b  = Qb;                                     //  (after entmax4 consumed BT1)
    __hip_bfloat16* Kmb  = (__hip_bfloat16*)(w + (200ll << 20));   //  4 MB (dead before BT1)
    __hip_bfloat16* xsb  = (__hip_bfloat16*)(w + (208ll << 20));   //  4 MB
    __hip_bfloat16* xfb  = (__hip_bfloat16*)(w + (212ll << 20));   //  4 MB
    __hip_bfloat16* wb   = (__hip_bfloat16*)(w + (216ll << 20));   //  0.75 MB
    __hip_bfloat16* VsTb = (__hip_bfloat16*)(w + (217ll << 20));   //  4 MB
    __hip_bfloat16* wqs_b = wb;
    __hip_bfloat16* wkf_b = wb + 65536;
    __hip_bfloat16* wvs_b = wb + 131072;
    __hip_bfloat16* cwq_b = wb + 196608;
    __hip_bfloat16* cwk_b = wb + 262144;
    __hip_bfloat16* wof_b = wb + 327680;

    float* out0 = (float*)d_out;
    float* out1 = out0 + 2097152;
    float* outC = out0 + 4194304;

    const dim3 blk(256);
    const dim3 blk8(512);

    // ---- conversions ----
    convert_bf16<<<dim3(2048), blk, 0, stream>>>(xs, xsb);
    convert_bf16<<<dim3(2048), blk, 0, stream>>>(xf, xfb);
    convert_bf16<<<dim3(8192), blk, 0, stream>>>(xs_fine, xsfb);
    convert_w6<<<dim3(64, 6), blk, 0, stream>>>(wqs, wkf, wvs, cfa_wq, cfa_wk, wof, wb);
    // S_s [8,4096,1024] fp32 -> SsTb [8,1024,4096] bf16
    transpose_to_bf16<<<dim3(32, 64, 8), blk, 0, stream>>>(S_s, SsTb, 4096, 1024);

    // ---- linears (MFMA): Y = X @ W^T + b ----
    mfma_gemm<__hip_bfloat16><<<dim3(64, 2, 1), blk, 0, stream>>>(xsb, wqs_b, bqs,
        Qb, nullptr, 8192, 256, 256, 0, 0, 0, 0, 1024, 1.f);
    mfma_gemm<__hip_bfloat16><<<dim3(64, 2, 1), blk, 0, stream>>>(xfb, wkf_b, bkf,
        Kmb, nullptr, 8192, 256, 256, 0, 0, 0, 0, 1024, 1.f);
    mfma_gemm<float><<<dim3(64, 2, 1), blk, 0, stream>>>(xsb, wvs_b, bvs,
        (float*)nullptr, VsTb, 8192, 256, 256, 0, 0, 0, 0, 1024, 1.f);  // Vs^T per batch
    mfma_gemm<__hip_bfloat16><<<dim3(64, 2, 1), blk, 0, stream>>>(xfb, cwq_b, cfa_bq,
        Qfb, nullptr, 8192, 256, 256, 0, 0, 0, 0, 1024, 1.f);
    mfma_gemm<__hip_bfloat16><<<dim3(256, 2, 1), blk, 0, stream>>>(xsfb, cwk_b, cfa_bk,
        Kfb, nullptr, 32768, 256, 256, 0, 0, 0, 0, 1024, 1.f);

    // ---- C_M = Q Km^T / 16 -> out[2] fp32 + CMT bf16 (per-batch transposed) ----
    mfma_gemm<float><<<dim3(8, 8, 8), blk, 0, stream>>>(Qb, Kmb, nullptr,
        outC, CMT, 1024, 1024, 256, 262144, 262144, 1048576, 1048576, 1024, 0.0625f);

    // ---- scores = Qf Kf^T / 16 -> Sb bf16 [8,1024,4096] (8-phase GEMM) ----
    gemm8p<__hip_bfloat16><<<dim3(4, 16, 8), blk8, 0, stream>>>(Qfb, Kfb, Sb,
        1024, 4096, 256, 262144, 1048576, 4194304, 0, 0, 0.0625f);

    // ---- P = entmax15 rows (in place, per-wave active-set solver) ----
    entmax_wave<64, false><<<dim3(2048), blk, 0, stream>>>(Sb, nullptr, nullptr, Sb);

    // ---- BT = P @ S_s (== bias_F^T) fp32, split-K x2 partials ----
    gemm8p<float><<<dim3(4, 4, 16), blk8, 0, stream>>>(Sb, SsTb, BT,
        1024, 1024, 4096, 4194304, 4194304, 1048576, 12582912, 1, 1.f);

    // ---- AfT = entmax15(CMT + log(max(BT0+BT1,eps))) rows -> bf16 ----
    entmax_wave<16, true><<<dim3(2048), blk, 0, stream>>>(CMT, BT, BT1, AfTb);

    // ---- T1 = AfT @ Vs -> bf16 ----
    mfma_gemm<__hip_bfloat16><<<dim3(8, 2, 8), blk, 0, stream>>>(AfTb, VsTb, nullptr,
        T1b, nullptr, 1024, 256, 1024, 1048576, 262144, 262144, 0, 1024, 1.f);

    // ---- out1 = T1 @ wof^T + bof ----
    mfma_gemm<float><<<dim3(64, 2, 1), blk, 0, stream>>>(T1b, wof_b, bof,
        out1, nullptr, 8192, 256, 256, 0, 0, 0, 0, 1024, 1.f);

    // ---- out0 = out1 + LayerNorm(xf) ----
    ln_add_kernel<<<dim3(8192), blk, 0, stream>>>(xf, fn_g, fn_b, out1, out0);
}

// Round 3
// 630.579 us; speedup vs baseline: 1.2443x; 1.0070x over previous
//
#include <hip/hip_runtime.h>
#include <hip/hip_bf16.h>

// ---------------------------------------------------------------------------
// Hie_Couple live subgraph (xs_/A_s/C_M_S/bias_S/Vf dead in reference).
// All GEMMs on bf16 MFMA. entmax-1.5 via per-wave register-resident
// active-set exact solver. This round: fused dual-output linears (Q|VsT,
// Km|Qf), LN fused into out1 epilogue (stats from the xf convert pass),
// bias concat folded into weight conversion. 17 -> 14 dispatches.
// ---------------------------------------------------------------------------

typedef __attribute__((ext_vector_type(8))) short short8;
typedef __attribute__((ext_vector_type(4))) float floatx4;

#define GLOBAL_AS __attribute__((address_space(1)))
#define LDS_AS    __attribute__((address_space(3)))

struct alignas(4) bf2 { __hip_bfloat16 x, y; };
struct alignas(8) bf4 { __hip_bfloat16 v[4]; };

// ============================ bf16 MFMA GEMM ===============================
// 128x128 tile kernel for the small/medium GEMMs.
// C[M,N] = scale * A[M,K] @ Bt[N,K]^T (+ bias[col]); strides per blockIdx.z.
// MODE 0: C (OutT) and/or CT (bf16, per-RB-row-group transposed), all cols.
// MODE 1: N=512 fused; col<256 -> C (bf16, ld 256); col>=256 -> CT
//         transposed path with col'=col-256 (N'=256, RB rows).
// MODE 2: N=512 fused; col<256 -> C (bf16, ld 256); col>=256 -> CT as a
//         PLAIN bf16 matrix (ld 256).
// MODE 3: C = fp32 out1 (ld N); also out0 = v + (xf-mu)*rstd*gam+bet using
//         per-row stats (LayerNorm residual fusion).
#define MT 128
#define NT 128
#define KT 64

template <typename OutT, int MODE>
__global__ __launch_bounds__(256) void mfma_gemm(
    const __hip_bfloat16* __restrict__ A, const __hip_bfloat16* __restrict__ Bt,
    const float* __restrict__ bias, OutT* __restrict__ C,
    __hip_bfloat16* __restrict__ CT,
    int M, int N, int K,
    long sA, long sB, long sC, long sCT, int RB, float scale,
    const float* __restrict__ xfp, const float2* __restrict__ stats,
    const float* __restrict__ gam, const float* __restrict__ bet,
    float* __restrict__ out0)
{
    __shared__ __hip_bfloat16 Asm[MT * KT];  // 16 KB
    __shared__ __hip_bfloat16 Bsm[NT * KT];  // 16 KB

    const int bz = blockIdx.z;
    const short* Ag = (const short*)(A + (long)bz * sA);
    const short* Bg = (const short*)(Bt + (long)bz * sB);

    const int m0 = blockIdx.x * MT;
    const int n0 = blockIdx.y * NT;

    const int tid  = threadIdx.x;
    const int lane = tid & 63;
    const int wm   = (tid >> 6 & 1) * 64;   // wave m-offset
    const int wn   = (tid >> 7) * 64;       // wave n-offset
    const int lm   = lane & 15;
    const int quad = lane >> 4;

    floatx4 acc[4][4] = {};

    for (int k0 = 0; k0 < K; k0 += KT) {
#pragma unroll
        for (int p = 0; p < 4; ++p) {
            const int idx = p * 256 + tid;
            const int row = idx >> 3;
            const int c8  = idx & 7;
            const int wbase = (p * 256 + (tid & 192)) * 16;  // wave-uniform base
            __builtin_amdgcn_global_load_lds(
                (const GLOBAL_AS void*)(Ag + (long)(m0 + row) * K + k0 + c8 * 8),
                (LDS_AS void*)((char*)Asm + wbase), 16, 0, 0);
            __builtin_amdgcn_global_load_lds(
                (const GLOBAL_AS void*)(Bg + (long)(n0 + row) * K + k0 + c8 * 8),
                (LDS_AS void*)((char*)Bsm + wbase), 16, 0, 0);
        }
        __syncthreads();

#pragma unroll
        for (int ks = 0; ks < KT / 32; ++ks) {
            short8 af[4], bf[4];
#pragma unroll
            for (int i = 0; i < 4; ++i) {
                af[i] = *(const short8*)((const short*)Asm + (wm + i * 16 + lm) * KT + ks * 32 + quad * 8);
                bf[i] = *(const short8*)((const short*)Bsm + (wn + i * 16 + lm) * KT + ks * 32 + quad * 8);
            }
#pragma unroll
            for (int i = 0; i < 4; ++i)
#pragma unroll
                for (int j = 0; j < 4; ++j)
                    acc[i][j] = __builtin_amdgcn_mfma_f32_16x16x32_bf16(af[i], bf[j], acc[i][j], 0, 0, 0);
        }
        __syncthreads();
    }

    float bb[4] = {0.f, 0.f, 0.f, 0.f};
    float gj[4], bj[4];
#pragma unroll
    for (int j = 0; j < 4; ++j) {
        const int colj = n0 + wn + lm + j * 16;
        if (bias) bb[j] = bias[colj];
        if (MODE == 3) { gj[j] = gam[colj]; bj[j] = bet[colj]; }
    }
    OutT* Cg = C ? C + (long)bz * sC : nullptr;
    __hip_bfloat16* CTg = CT ? CT + (long)bz * sCT : nullptr;

#pragma unroll
    for (int i = 0; i < 4; ++i) {
        const int row0 = m0 + wm + i * 16 + quad * 4;
#pragma unroll
        for (int j = 0; j < 4; ++j) {
            const int col = n0 + wn + lm + j * 16;
            float v[4];
#pragma unroll
            for (int r = 0; r < 4; ++r) v[r] = acc[i][j][r] * scale + bb[j];

            if (MODE == 0) {
                if (Cg) {
#pragma unroll
                    for (int r = 0; r < 4; ++r)
                        Cg[(long)(row0 + r) * N + col] = (OutT)v[r];
                }
                if (CTg) {
                    bf4 pk;
#pragma unroll
                    for (int r = 0; r < 4; ++r) pk.v[r] = (__hip_bfloat16)v[r];
                    const long b_i = row0 / RB, r_i = row0 % RB;
                    *(bf4*)(CTg + b_i * (long)N * RB + (long)col * RB + r_i) = pk;
                }
            } else if (MODE == 1) {
                if (col < 256) {
#pragma unroll
                    for (int r = 0; r < 4; ++r)
                        Cg[(long)(row0 + r) * 256 + col] = (OutT)v[r];
                } else {
                    bf4 pk;
#pragma unroll
                    for (int r = 0; r < 4; ++r) pk.v[r] = (__hip_bfloat16)v[r];
                    const long b_i = row0 / RB, r_i = row0 % RB;
                    *(bf4*)(CTg + b_i * (long)256 * RB + (long)(col - 256) * RB + r_i) = pk;
                }
            } else if (MODE == 2) {
                if (col < 256) {
#pragma unroll
                    for (int r = 0; r < 4; ++r)
                        Cg[(long)(row0 + r) * 256 + col] = (OutT)v[r];
                } else {
#pragma unroll
                    for (int r = 0; r < 4; ++r)
                        CTg[(long)(row0 + r) * 256 + (col - 256)] = (__hip_bfloat16)v[r];
                }
            } else {  // MODE 3: out1 + LN residual into out0
#pragma unroll
                for (int r = 0; r < 4; ++r) {
                    const long idx = (long)(row0 + r) * N + col;
                    Cg[idx] = (OutT)v[r];
                    const float2 st = stats[row0 + r];
                    out0[idx] = v[r] + (xfp[idx] - st.x) * st.y * gj[j] + bj[j];
                }
            }
        }
    }
}

// ======================= 256x256 8-phase MFMA GEMM =========================
// C[M,N] = scale * A[M,K']@Bt[N,K']^T, per-batch strides, optional split-K:
// blockIdx.z = batch*(1<<ksh) + kh; each block does K/(1<<ksh) of the K dim,
// writing its partial to C + batch*sC + kh*sCsplit.
// 512 threads = 8 waves (2M x 4N), per-wave 128x64 output (acc[2][2][4][2]).
// BK=64; LDS 128 KB (A,B x 2 buffers); 4 phases/K-tile x 16 MFMA.
// T2: slot ^= (row&7) swizzle (inverse-swizzled global src, swizzled ds_read).
// T3/T4: one half-tile staged per phase, counted vmcnt (never 0 mid-loop).
// T5: setprio around each MFMA cluster.  T1: XCD-bijective block swizzle.
//
// Stage schedule (tile t computed from buf b=t&1, nb=b^1):
//   ph1 reads A0,B0(t) | stages B1(t+1)->nb | vmcnt(4) guarantees A1(t)
//   ph2 reads A1(t)    | stages A0(t+1)->nb
//   ph3 reads B1(t)    | stages A1(t+1)->nb
//   ph4 re-reads A0(t) | stages B0(t+2)->b  | vmcnt(4) guarantees B0,B1,A0(t+1)
// Every staged region's last reader finished >=1 barrier before the issue.

#define G8_LDSA(B_, QR_) do { \
  _Pragma("unroll") for (int i_ = 0; i_ < 4; ++i_) { \
  _Pragma("unroll") for (int ks_ = 0; ks_ < 2; ++ks_) { \
    const int row_ = wm + (QR_) * 64 + i_ * 16 + lm; \
    af[i_][ks_] = *(const short8*)(lds_c + (B_) * 32768 + row_ * 128 + ((((ks_ << 2) | qd) ^ sw) << 4)); } } } while (0)

#define G8_LDSB(B_, QC_) do { \
  _Pragma("unroll") for (int j_ = 0; j_ < 2; ++j_) { \
  _Pragma("unroll") for (int ks_ = 0; ks_ < 2; ++ks_) { \
    const int row_ = wn + (QC_) * 32 + j_ * 16 + lm; \
    bf[j_][ks_] = *(const short8*)(lds_c + 65536 + (B_) * 32768 + row_ * 128 + ((((ks_ << 2) | qd) ^ sw) << 4)); } } } while (0)

#define G8_MFMA(QR_, QC_) do { \
  __builtin_amdgcn_s_setprio(1); \
  _Pragma("unroll") for (int ks_ = 0; ks_ < 2; ++ks_) { \
  _Pragma("unroll") for (int i_ = 0; i_ < 4; ++i_) { \
  _Pragma("unroll") for (int j_ = 0; j_ < 2; ++j_) { \
    acc[QR_][QC_][i_][j_] = __builtin_amdgcn_mfma_f32_16x16x32_bf16( \
        af[i_][ks_], bf[j_][ks_], acc[QR_][QC_][i_][j_], 0, 0, 0); } } } \
  __builtin_amdgcn_s_setprio(0); } while (0)

// stage one 128x64 half-tile (16 KB): 2 x global_load_lds(16B) per thread.
// LDS dest is linear; global source column pre-swizzled (rule #21 involution).
#define G8_STAGE(GP_, LB_, B_, H_, KT_) do { \
  _Pragma("unroll") for (int n_ = 0; n_ < 2; ++n_) { \
    const int c_   = n_ * 512 + tid; \
    const int row_ = (H_) * 128 + (c_ >> 3); \
    const int sl_  = (c_ & 7) ^ (row_ & 7); \
    __builtin_amdgcn_global_load_lds( \
      (const GLOBAL_AS void*)((GP_) + (long)row_ * K + (long)kbase + (long)(KT_) * 64 + sl_ * 8), \
      (LDS_AS void*)(lds_c + (LB_) + (B_) * 32768 + (H_) * 16384 + (n_ * 512 + (tid & 448)) * 16), \
      16, 0, 0); } } while (0)

template <typename OutT>
__global__ __launch_bounds__(512, 2) void gemm8p(
    const __hip_bfloat16* __restrict__ A, const __hip_bfloat16* __restrict__ Bt,
    OutT* __restrict__ C,
    int M, int N, int K,            // per-batch dims (K = full per-batch K)
    long sA, long sB, long sC, long sCsplit,
    int ksh, float scale)
{
    __shared__ char lds_c[131072];  // A: [0,64K) = 2 x 32KB bufs; B: [64K,128K)

    // ---- T1: bijective XCD swizzle of the linear block id ----
    const int gx = gridDim.x, gy = gridDim.y;
    const int nwg = gx * gy * gridDim.z;
    int lid = blockIdx.x + gx * (blockIdx.y + gy * blockIdx.z);
    lid = (lid & 7) * (nwg >> 3) + (lid >> 3);     // nwg % 8 == 0 at our grids
    const int bx = lid % gx;
    const int t1 = lid / gx;
    const int by = t1 % gy;
    const int bz = t1 / gy;

    const int batch = bz >> ksh;
    const int kh    = bz & ((1 << ksh) - 1);
    const int Kblk  = K >> ksh;
    const int kbase = kh * Kblk;
    const int NTK   = Kblk >> 6;                   // K-tiles (>= 2 required)

    const int m0 = bx * 256;
    const int n0 = by * 256;

    const int tid  = threadIdx.x;
    const int lane = tid & 63;
    const int lm   = lane & 15;
    const int qd   = lane >> 4;
    const int sw   = lm & 7;
    const int wid  = tid >> 6;
    const int wm   = (wid >> 2) * 128;             // wave m-offset (2 rows)
    const int wn   = (wid & 3) * 64;               // wave n-offset (4 cols)

    const short* Ag2 = (const short*)A + (long)batch * sA + (long)m0 * K;
    const short* Bg2 = (const short*)Bt + (long)batch * sB + (long)n0 * K;

    floatx4 acc[2][2][4][2] = {};
    short8 af[4][2];
    short8 bf[2][2];

    // ---- prologue: tile0 fully + B0(tile1); leave B0(1) in flight ----
    G8_STAGE(Bg2, 65536, 0, 0, 0);
    G8_STAGE(Bg2, 65536, 0, 1, 0);
    G8_STAGE(Ag2, 0,     0, 0, 0);
    G8_STAGE(Ag2, 0,     0, 1, 0);
    if (NTK > 1) {
        G8_STAGE(Bg2, 65536, 1, 0, 1);
        asm volatile("s_waitcnt vmcnt(2)" ::: "memory");
    } else {
        asm volatile("s_waitcnt vmcnt(0)" ::: "memory");
    }
    __builtin_amdgcn_s_barrier();

    for (int t = 0; t < NTK; ++t) {
        const int b  = t & 1;
        const int nb = b ^ 1;
        const bool st1 = (t + 1 < NTK);
        const bool st2 = (t + 2 < NTK);

        // ---- phase 1: quad (0,0) ----
        G8_LDSA(b, 0);
        G8_LDSB(b, 0);
        if (st1) G8_STAGE(Bg2, 65536, nb, 1, t + 1);
        __builtin_amdgcn_s_barrier();
        G8_MFMA(0, 0);
        if (st1) asm volatile("s_waitcnt vmcnt(4)" ::: "memory");
        else     asm volatile("s_waitcnt vmcnt(0)" ::: "memory");
        __builtin_amdgcn_s_barrier();

        // ---- phase 2: quad (1,0) ----
        G8_LDSA(b, 1);
        if (st1) G8_STAGE(Ag2, 0, nb, 0, t + 1);
        __builtin_amdgcn_s_barrier();
        G8_MFMA(1, 0);
        __builtin_amdgcn_s_barrier();

        // ---- phase 3: quad (1,1) ----
        G8_LDSB(b, 1);
        if (st1) G8_STAGE(Ag2, 0, nb, 1, t + 1);
        __builtin_amdgcn_s_barrier();
        G8_MFMA(1, 1);
        __builtin_amdgcn_s_barrier();

        // ---- phase 4: quad (0,1) (A0 re-read) ----
        G8_LDSA(b, 0);
        if (st2) G8_STAGE(Bg2, 65536, b, 0, t + 2);
        __builtin_amdgcn_s_barrier();
        G8_MFMA(0, 1);
        if (st2) asm volatile("s_waitcnt vmcnt(4)" ::: "memory");
        else     asm volatile("s_waitcnt vmcnt(2)" ::: "memory");
        __builtin_amdgcn_s_barrier();
    }

    // ---- epilogue: C/D layout col = lm(+16j...), row = qd*4+r ----
    OutT* Cg = C + (long)batch * sC + (long)kh * sCsplit;
#pragma unroll
    for (int qr = 0; qr < 2; ++qr)
#pragma unroll
    for (int i = 0; i < 4; ++i) {
        const int row0 = m0 + wm + qr * 64 + i * 16 + qd * 4;
#pragma unroll
        for (int qc = 0; qc < 2; ++qc)
#pragma unroll
        for (int j = 0; j < 2; ++j) {
            const int col = n0 + wn + qc * 32 + j * 16 + lm;
#pragma unroll
            for (int r = 0; r < 4; ++r)
                Cg[(long)(row0 + r) * N + col] = (OutT)(acc[qr][qc][i][j][r] * scale);
        }
    }
}

// ======================= fp32 -> bf16 converters ===========================
__global__ __launch_bounds__(256) void convert_bf16(
    const float* __restrict__ src, __hip_bfloat16* __restrict__ dst)
{
    const long g = ((long)blockIdx.x * 256 + threadIdx.x) * 4;
    const float4 v = *(const float4*)(src + g);
    bf4 o;
    o.v[0] = (__hip_bfloat16)v.x; o.v[1] = (__hip_bfloat16)v.y;
    o.v[2] = (__hip_bfloat16)v.z; o.v[3] = (__hip_bfloat16)v.w;
    *(bf4*)(dst + g) = o;
}

// xf convert + per-row LayerNorm stats (mu, rstd). Rows are 256 fp32; each
// 64-lane wave owns exactly one row (4 elems/lane) -> butterfly reduce.
__global__ __launch_bounds__(256) void convert_xf_stats(
    const float* __restrict__ src, __hip_bfloat16* __restrict__ dst,
    float2* __restrict__ stats)
{
    const long g = ((long)blockIdx.x * 256 + threadIdx.x) * 4;
    const float4 v = *(const float4*)(src + g);
    bf4 o;
    o.v[0] = (__hip_bfloat16)v.x; o.v[1] = (__hip_bfloat16)v.y;
    o.v[2] = (__hip_bfloat16)v.z; o.v[3] = (__hip_bfloat16)v.w;
    *(bf4*)(dst + g) = o;

    float s1 = v.x + v.y + v.z + v.w;
    float s2 = v.x * v.x + v.y * v.y + v.z * v.z + v.w * v.w;
    for (int off = 32; off > 0; off >>= 1) {
        s1 += __shfl_xor(s1, off);
        s2 += __shfl_xor(s2, off);
    }
    if ((threadIdx.x & 63) == 0) {
        const int row = blockIdx.x * 4 + (threadIdx.x >> 6);
        const float mu  = s1 * (1.0f / 256.0f);
        const float var = s2 * (1.0f / 256.0f) - mu * mu;
        stats[row] = make_float2(mu, rsqrtf(var + 1e-5f));
    }
}

// 6 weights [256,256] -> contiguous bf16 slots of 65536; y==6 concats the
// 4 fused-linear bias vectors into biasc[1024] fp32.
__global__ __launch_bounds__(256) void convert_w6(
    const float* w0, const float* w1, const float* w2,
    const float* w3, const float* w4, const float* w5,
    const float* b0, const float* b1, const float* b2, const float* b3,
    __hip_bfloat16* __restrict__ dst, float* __restrict__ biasc)
{
    if (blockIdx.y == 6) {
        if (blockIdx.x < 4) {
            const float* bs[4] = {b0, b1, b2, b3};
            biasc[blockIdx.x * 256 + threadIdx.x] = bs[blockIdx.x][threadIdx.x];
        }
        return;
    }
    const float* srcs[6] = {w0, w1, w2, w3, w4, w5};
    const float* s = srcs[blockIdx.y];
    const long off = (long)blockIdx.y * 65536;
    const long g = ((long)blockIdx.x * 256 + threadIdx.x) * 4;
    const float4 v = *(const float4*)(s + g);
    bf4 o;
    o.v[0] = (__hip_bfloat16)v.x; o.v[1] = (__hip_bfloat16)v.y;
    o.v[2] = (__hip_bfloat16)v.z; o.v[3] = (__hip_bfloat16)v.w;
    *(bf4*)(dst + off + g) = o;
}

// src [bz][R][C] fp32 -> dst [bz][C][R] bf16.  64(r) x 32(c) tiles; stores
// are bf2 (4B/lane, 128B wave segments).
__global__ __launch_bounds__(256) void transpose_to_bf16(
    const float* __restrict__ src, __hip_bfloat16* __restrict__ dst, int R, int C)
{
    __shared__ __hip_bfloat16 tt[32][66];
    const long bo = (long)blockIdx.z * R * C;
    const int tx = threadIdx.x & 31;
    const int ty = threadIdx.x >> 5;            // 0..7
    const int c0 = blockIdx.x * 32;
    const int r0 = blockIdx.y * 64;
#pragma unroll
    for (int p = 0; p < 8; ++p)
        tt[tx][p * 8 + ty] = (__hip_bfloat16)src[bo + (long)(r0 + p * 8 + ty) * C + c0 + tx];
    __syncthreads();
#pragma unroll
    for (int p = 0; p < 4; ++p) {
        const int c = p * 8 + ty;
        bf2 o;
        o.x = tt[c][2 * tx];
        o.y = tt[c][2 * tx + 1];
        *(bf2*)(dst + bo + (long)(c0 + c) * R + r0 + 2 * tx) = o;
    }
}

// ============================== entmax-1.5 =================================
// Per-wave: one row of L = EPW*64 bf16 per 64-lane wave (EPW f32 VGPRs/lane).
// No barriers, no LDS; all reductions are 6-level __shfl_xor butterflies.
// z = Zin (+ log(max(Bias+Bias2,1e-6)) if HB; Bias2 = split-K partial).
// Solver: active-set exact solve; fixed point == exact root. 12 iters cap
// + 2 monotone Newton polish steps.
template <int EPW, bool HB>
__global__ __launch_bounds__(256) void entmax_wave(
    const __hip_bfloat16* __restrict__ Zin, const float* __restrict__ Bias,
    const float* __restrict__ Bias2, __hip_bfloat16* __restrict__ Out)
{
    constexpr int L = EPW * 64;
    constexpr int NC = EPW / 8;             // 16B chunks per lane
    const int lane = threadIdx.x & 63;
    const int wid  = threadIdx.x >> 6;
    const long base = ((long)blockIdx.x * 4 + wid) * (long)L;

    const short8* Zp = (const short8*)(Zin + base);
    float z[EPW];
    float lmax = -3.4e38f;
#pragma unroll
    for (int c = 0; c < NC; ++c) {
        const int e0  = c * 8;
        const int idx = (c * 64 + lane) * 8;     // element index within row
        const short8 u = Zp[c * 64 + lane];
        float bb[8];
        if (HB) {
            const float4 b0 = *(const float4*)(Bias  + base + idx);
            const float4 b4 = *(const float4*)(Bias  + base + idx + 4);
            const float4 c0 = *(const float4*)(Bias2 + base + idx);
            const float4 c4 = *(const float4*)(Bias2 + base + idx + 4);
            bb[0] = b0.x + c0.x; bb[1] = b0.y + c0.y;
            bb[2] = b0.z + c0.z; bb[3] = b0.w + c0.w;
            bb[4] = b4.x + c4.x; bb[5] = b4.y + c4.y;
            bb[6] = b4.z + c4.z; bb[7] = b4.w + c4.w;
        }
#pragma unroll
        for (int q = 0; q < 8; ++q) {
            float v = __uint_as_float(((unsigned)(unsigned short)u[q]) << 16);
            if (HB) v += logf(fmaxf(bb[q], 1e-6f));
            z[e0 + q] = v;
            lmax = fmaxf(lmax, v);
        }
    }
    for (int o = 32; o > 0; o >>= 1) lmax = fmaxf(lmax, __shfl_xor(lmax, o));
#pragma unroll
    for (int e = 0; e < EPW; ++e) z[e] = (z[e] - lmax) * 0.5f;

    // active-set exact-solve iterations (fixed point == exact solution)
    float tau = -1.0f;
    for (int it = 0; it < 12; ++it) {
        float s1 = 0.f, s2 = 0.f, kf = 0.f;
#pragma unroll
        for (int e = 0; e < EPW; ++e) {
            const float d = fmaxf(z[e] - tau, 0.f);
            s2 = fmaf(d, d, s2);
            s1 += d;
            kf += (d > 0.f) ? 1.f : 0.f;
        }
        for (int o = 32; o > 0; o >>= 1) {
            s1 += __shfl_xor(s1, o);
            s2 += __shfl_xor(s2, o);
            kf += __shfl_xor(kf, o);
        }
        if (kf < 0.5f) break;                    // degenerate guard
        const float disc  = fmaxf(fmaf(s1, s1, -kf * (s2 - 1.f)), 0.f);
        const float delta = (s1 - sqrtf(disc)) / kf;
        tau += delta;
        if (!(fabsf(delta) > 2e-6f)) break;
    }
    // Newton polish (monotone near root; no-op if already converged)
#pragma unroll
    for (int it = 0; it < 2; ++it) {
        float f = 0.f, g = 0.f;
#pragma unroll
        for (int e = 0; e < EPW; ++e) {
            const float d = fmaxf(z[e] - tau, 0.f);
            f = fmaf(d, d, f);
            g += d;
        }
        for (int o = 32; o > 0; o >>= 1) {
            f += __shfl_xor(f, o);
            g += __shfl_xor(g, o);
        }
        if (g > 0.f) tau += (f - 1.0f) / (2.0f * g);
    }

#pragma unroll
    for (int c = 0; c < NC; ++c) {
        const int e0 = c * 8;
        union { short8 s; __hip_bfloat16 h[8]; } o;
#pragma unroll
        for (int q = 0; q < 8; ++q) {
            const float d = fmaxf(z[e0 + q] - tau, 0.f);
            o.h[q] = (__hip_bfloat16)(d * d);
        }
        *((short8*)(Out + base) + c * 64 + lane) = o.s;
    }
}

// ================================ driver ===================================
extern "C" void kernel_launch(void* const* d_in, const int* in_sizes, int n_in,
                              void* d_out, int out_size, void* d_ws, size_t ws_size,
                              hipStream_t stream)
{
    (void)in_sizes; (void)n_in; (void)out_size; (void)ws_size;

    const float* xs      = (const float*)d_in[0];
    const float* xf      = (const float*)d_in[1];
    const float* xs_fine = (const float*)d_in[2];
    const float* S_s     = (const float*)d_in[4];
    const float* cfa_wq  = (const float*)d_in[6];
    const float* cfa_bq  = (const float*)d_in[7];
    const float* cfa_wk  = (const float*)d_in[8];
    const float* cfa_bk  = (const float*)d_in[9];
    const float* wqs     = (const float*)d_in[14];
    const float* bqs     = (const float*)d_in[15];
    const float* wkf     = (const float*)d_in[16];
    const float* bkf     = (const float*)d_in[17];
    const float* wvs     = (const float*)d_in[18];
    const float* bvs     = (const float*)d_in[19];
    const float* wof     = (const float*)d_in[24];
    const float* bof     = (const float*)d_in[25];
    const float* fn_g    = (const float*)d_in[28];
    const float* fn_b    = (const float*)d_in[29];

    // ---- workspace layout (MB offsets; peak ~221 MB, 224 MiB proven) ----
    char* w = (char*)d_ws;
    __hip_bfloat16* Sb   = (__hip_bfloat16*)(w);                   // 64 MB
    __hip_bfloat16* xsfb = (__hip_bfloat16*)(w);                   // 16 MB (dead before Sb written)
    __hip_bfloat16* SsTb = (__hip_bfloat16*)(w + (64ll  << 20));   // 64 MB
    __hip_bfloat16* AfTb = (__hip_bfloat16*)(w + (64ll  << 20));   // 16 MB (after BT gemm)
    float*          BT   = (float*)         (w + (128ll << 20));   // 32 MB (split-K partial 0)
    __hip_bfloat16* CMT  = (__hip_bfloat16*)(w + (160ll << 20));   // 16 MB
    float*          BT1  = (float*)         (w + (176ll << 20));   // 32 MB partial 1 (over dead Kfb/Qfb/Qb/Kmb)
    __hip_bfloat16* Kfb  = (__hip_bfloat16*)(w + (176ll << 20));   // 16 MB (dead before BT1 written)
    __hip_bfloat16* Qfb  = (__hip_bfloat16*)(w + (192ll << 20));   //  4 MB (dead before BT1)
    __hip_bfloat16* Qb   = (__hip_bfloat16*)(w + (196ll << 20));   //  4 MB (dead before BT1)
    __hip_bfloat16* T1b  = Qb;                                     //  (after entmax4 consumed BT1)
    __hip_bfloat16* Kmb  = (__hip_bfloat16*)(w + (200ll << 20));   //  4 MB (dead before BT1)
    __hip_bfloat16* xsb  = (__hip_bfloat16*)(w + (208ll << 20));   //  4 MB
    __hip_bfloat16* xfb  = (__hip_bfloat16*)(w + (212ll << 20));   //  4 MB
    __hip_bfloat16* wb   = (__hip_bfloat16*)(w + (216ll << 20));   //  768 KB (6 slots)
    float*          biasc = (float*)(w + (216ll << 20) + 786432);  //  4 KB
    float2*         stats = (float2*)(w + (216ll << 20) + 790528); // 64 KB
    __hip_bfloat16* VsTb = (__hip_bfloat16*)(w + (217ll << 20));   //  4 MB
    // slot order: [wqs | wvs | wkf | cwq | cwk | wof]
    __hip_bfloat16* wQV_b = wb;                 // rows 0-255 wqs, 256-511 wvs
    __hip_bfloat16* wKQ_b = wb + 131072;        // rows 0-255 wkf, 256-511 cwq
    __hip_bfloat16* cwk_b = wb + 262144;
    __hip_bfloat16* wof_b = wb + 327680;

    float* out0 = (float*)d_out;
    float* out1 = out0 + 2097152;
    float* outC = out0 + 4194304;

    const dim3 blk(256);
    const dim3 blk8(512);

    // ---- conversions (+ LN stats for xf, + bias concat) ----
    convert_bf16<<<dim3(2048), blk, 0, stream>>>(xs, xsb);
    convert_xf_stats<<<dim3(2048), blk, 0, stream>>>(xf, xfb, stats);
    convert_bf16<<<dim3(8192), blk, 0, stream>>>(xs_fine, xsfb);
    convert_w6<<<dim3(64, 7), blk, 0, stream>>>(wqs, wvs, wkf, cfa_wq, cfa_wk, wof,
        bqs, bvs, bkf, cfa_bq, wb, biasc);
    // S_s [8,4096,1024] fp32 -> SsTb [8,1024,4096] bf16
    transpose_to_bf16<<<dim3(32, 64, 8), blk, 0, stream>>>(S_s, SsTb, 4096, 1024);

    // ---- fused linears: xs -> [Q | Vs^T], xf -> [Km | Qf] ----
    mfma_gemm<__hip_bfloat16, 1><<<dim3(64, 4, 1), blk, 0, stream>>>(xsb, wQV_b,
        biasc, Qb, VsTb, 8192, 512, 256, 0, 0, 0, 0, 1024, 1.f,
        nullptr, nullptr, nullptr, nullptr, nullptr);
    mfma_gemm<__hip_bfloat16, 2><<<dim3(64, 4, 1), blk, 0, stream>>>(xfb, wKQ_b,
        biasc + 512, Kmb, Qfb, 8192, 512, 256, 0, 0, 0, 0, 1024, 1.f,
        nullptr, nullptr, nullptr, nullptr, nullptr);
    mfma_gemm<__hip_bfloat16, 0><<<dim3(256, 2, 1), blk, 0, stream>>>(xsfb, cwk_b,
        cfa_bk, Kfb, nullptr, 32768, 256, 256, 0, 0, 0, 0, 1024, 1.f,
        nullptr, nullptr, nullptr, nullptr, nullptr);

    // ---- C_M = Q Km^T / 16 -> out[2] fp32 + CMT bf16 (per-batch transposed) ----
    mfma_gemm<float, 0><<<dim3(8, 8, 8), blk, 0, stream>>>(Qb, Kmb, nullptr,
        outC, CMT, 1024, 1024, 256, 262144, 262144, 1048576, 1048576, 1024, 0.0625f,
        nullptr, nullptr, nullptr, nullptr, nullptr);

    // ---- scores = Qf Kf^T / 16 -> Sb bf16 [8,1024,4096] (8-phase GEMM) ----
    gemm8p<__hip_bfloat16><<<dim3(4, 16, 8), blk8, 0, stream>>>(Qfb, Kfb, Sb,
        1024, 4096, 256, 262144, 1048576, 4194304, 0, 0, 0.0625f);

    // ---- P = entmax15 rows (in place, per-wave active-set solver) ----
    entmax_wave<64, false><<<dim3(2048), blk, 0, stream>>>(Sb, nullptr, nullptr, Sb);

    // ---- BT = P @ S_s (== bias_F^T) fp32, split-K x2 partials ----
    gemm8p<float><<<dim3(4, 4, 16), blk8, 0, stream>>>(Sb, SsTb, BT,
        1024, 1024, 4096, 4194304, 4194304, 1048576, 12582912, 1, 1.f);

    // ---- AfT = entmax15(CMT + log(max(BT0+BT1,eps))) rows -> bf16 ----
    entmax_wave<16, true><<<dim3(2048), blk, 0, stream>>>(CMT, BT, BT1, AfTb);

    // ---- T1 = AfT @ Vs -> bf16 ----
    mfma_gemm<__hip_bfloat16, 0><<<dim3(8, 2, 8), blk, 0, stream>>>(AfTb, VsTb,
        nullptr, T1b, nullptr, 1024, 256, 1024, 1048576, 262144, 262144, 0, 1024, 1.f,
        nullptr, nullptr, nullptr, nullptr, nullptr);

    // ---- out1 = T1 @ wof^T + bof; out0 = out1 + LN(xf) (fused epilogue) ----
    mfma_gemm<float, 3><<<dim3(64, 2, 1), blk, 0, stream>>>(T1b, wof_b, bof,
        out1, nullptr, 8192, 256, 256, 0, 0, 0, 0, 1024, 1.f,
        xf, stats, fn_g, fn_b, out0);
}